// Round 5
// baseline (6002.788 us; speedup 1.0000x reference)
//
#include <hip/hip_runtime.h>

// ---------------------------------------------------------------------------
// GaussianGradientLSTMPolicy on MI355X
//   A0: fp32 -> bf16 converts (x, weights), bias fusions
//   A2: shared = leaky_relu(x @ W1^T + b1)                  [131072 x 256]
//   A3: ig     = shared @ W_ih^T + (b_ih + b_hh)  (permuted)[131072 x 1024]
//   B : persistent-register LSTM scan, block pairs exchange h halves
//       R8: single-poller wave + K-split MFMA overlap
//         - ONLY WAVE 0 polls the partner's 8KB half (8 dwordx4/lane,
//           alternating sc0 / sc0+sc1 legs -- same always-live dual-path
//           protocol as R7) and scatters it to LDS. Waves 1-7 execute NO
//           vmcnt in the loop: publishes/hid/pre stores drain in the
//           background while they park at lgkm-only barriers. Removes the
//           8-wave spin contention and the per-wave store-ack drains that
//           R4-R7 kept paying.
//         - K-split: the 16 MFMAs over the block's OWN h-half (k-slices
//           ph*4..+3) run BEFORE the poll; partner-half MFMAs after B2.
//           Partner visibility latency overlaps own-half compute.
//         - acc-init (ig[t] use) before B2 in all waves => all ig[t] loads
//           complete before any post-B2 hid[t] store (alias safety without
//           delayed stores). ig[t+1] prefetch after B2 (off the poller's
//           critical segment).
//         - 2 lgkm-only barriers/step (B1 own-half LDS, B2 partner half).
//       XCD-discovery pairing kept from R7 (same-XCD pairs preferred).
//   C : means = tanh(pre@Wm^T+bm), stds = softplus(pre@Ws^T+bs)+eps
// Aliasing:
//   - x_bf16 lives in d_out[0 .. 32MiB) (means+stds region), consumed by A2
//   - ctl (pairing table) lives in the LAST 2KB of that region: dead after
//     A2 reads x_bf16, zeroed by k_zero_ctl (after A2), used by the scan,
//     overwritten by the heads GEMM (stds) afterwards.
//   - ig (bf16) lives in the d_out hidden_outputs region with a PERMUTED
//     layout such that the bytes block (g,ph) reads as ig[t] are exactly the
//     bytes it writes as hid[t]:
//       idx_u16(t,b,q,ph,jl) = t*262144 + (q>>1)*131072 + b*512
//                              + ph*256 + (q&1)*128 + jl
// ---------------------------------------------------------------------------

typedef __attribute__((ext_vector_type(8))) short short8;
typedef __attribute__((ext_vector_type(4))) float f32x4;
typedef __attribute__((ext_vector_type(4))) unsigned short u16x4;
typedef __attribute__((ext_vector_type(4))) unsigned int u32x4;
typedef unsigned short u16;
typedef unsigned int   u32;

// ws layout (bytes)
constexpr size_t OFF_SH   = 0;                      // shared bf16   67108864
constexpr size_t OFF_PRE  = 67108864;               // pre bf16      67108864
constexpr size_t OFF_W1   = 134217728;              // W1 bf16          65536
constexpr size_t OFF_WIH  = OFF_W1   + 65536;       // W_ih bf16       524288
constexpr size_t OFF_WHH  = OFF_WIH  + 524288;      // W_hh bf16       524288
constexpr size_t OFF_WCAT = OFF_WHH  + 524288;      // [Wm;Ws] bf16     32768
constexpr size_t OFF_BIG  = OFF_WCAT + 32768;       // b_ih+b_hh f32     4096
constexpr size_t OFF_BCAT = OFF_BIG  + 4096;        // [bm;bs] f32        256
constexpr size_t OFF_X    = OFF_BCAT + 256;         // h2 exchange     524288
// total ~136 MB

__device__ __forceinline__ u16 f2bf(float f) {
  union { float f; u32 u; } v; v.f = f;
  u32 u = v.u;
  return (u16)((u + 0x7fffu + ((u >> 16) & 1u)) >> 16);   // RNE
}
__device__ __forceinline__ float bf2f(u16 h) {
  union { u32 u; float f; } v; v.u = ((u32)h) << 16; return v.f;
}
__device__ __forceinline__ float fsigmoid(float x) {
  return 1.0f / (1.0f + __expf(-x));
}
__device__ __forceinline__ float ftanh(float x) {
  return 1.0f - 2.0f / (__expf(2.0f * x) + 1.0f);
}

// ---------------------------------------------------------------- converts
__global__ void k_conv_x(const float* __restrict__ x, u16* __restrict__ o) {
  const size_t stride = (size_t)gridDim.x * blockDim.x;
  for (size_t i = (size_t)blockIdx.x * blockDim.x + threadIdx.x;
       i < 16777216 / 4; i += stride) {
    f32x4 v = ((const f32x4*)x)[i];
    u16x4 r;
    r[0] = f2bf(v[0]); r[1] = f2bf(v[1]); r[2] = f2bf(v[2]); r[3] = f2bf(v[3]);
    ((u16x4*)o)[i] = r;
  }
}

__global__ void k_small(const float* __restrict__ W1, const float* __restrict__ Wih,
                        const float* __restrict__ Whh, const float* __restrict__ Wm,
                        const float* __restrict__ Ws,  const float* __restrict__ bih,
                        const float* __restrict__ bhh, const float* __restrict__ bm,
                        const float* __restrict__ bs,
                        u16* __restrict__ W1b, u16* __restrict__ Wihb,
                        u16* __restrict__ Whhb, u16* __restrict__ Wcatb,
                        float* __restrict__ bigv, float* __restrict__ bcatv) {
  const int stride = gridDim.x * blockDim.x;
  const int i0 = blockIdx.x * blockDim.x + threadIdx.x;
  for (int i = i0; i < 32768;  i += stride) W1b[i]  = f2bf(W1[i]);
  for (int i = i0; i < 262144; i += stride) Wihb[i] = f2bf(Wih[i]);
  for (int i = i0; i < 262144; i += stride) Whhb[i] = f2bf(Whh[i]);
  for (int i = i0; i < 8192;   i += stride) Wcatb[i]        = f2bf(Wm[i]);
  for (int i = i0; i < 8192;   i += stride) Wcatb[8192 + i] = f2bf(Ws[i]);
  for (int i = i0; i < 1024;   i += stride) bigv[i] = bih[i] + bhh[i];
  for (int i = i0; i < 32;     i += stride) bcatv[i]      = bm[i];
  for (int i = i0; i < 32;     i += stride) bcatv[32 + i] = bs[i];
}

// zero the pairing/control area (system scope -> LLC is the point of truth)
__global__ void k_zero_ctl(u32* __restrict__ ctl) {
  if (threadIdx.x < 512)
    __hip_atomic_store(&ctl[threadIdx.x], 0u, __ATOMIC_RELAXED,
                       __HIP_MEMORY_SCOPE_SYSTEM);
}

// ------------------------------------------------------------ generic GEMM
// C[M,N] = epi(A[M,K] @ W[N,K]^T + bias), bf16 in, fp32 acc.
// EPI 0: leaky_relu -> bf16 out (ld = N)
// EPI 1: bf16 out, permuted so scan-block (g,ph)'s ig[t] bytes == its hid[t]
// EPI 2: heads: n<32 -> tanh -> means(f32); n>=32 -> softplus+eps -> stds
template <int K, int EPI>
__global__ __launch_bounds__(256) void gemm_bt(const u16* __restrict__ A,
                                               const u16* __restrict__ W,
                                               const float* __restrict__ bias,
                                               void* __restrict__ outp, int N) {
  __shared__ __align__(16) u16 As[64 * 40];   // +8 pad: 2-way banks only
  __shared__ __align__(16) u16 Wt[64 * 40];
  const int tid  = threadIdx.x;
  const int lane = tid & 63;
  const int wv   = tid >> 6;
  const int quad = lane >> 4, l15 = lane & 15;
  const int wm = wv & 1, wn = wv >> 1;
  const size_t m0 = (size_t)blockIdx.x * 64;
  const int    n0 = blockIdx.y * 64;
  const int ldr  = tid >> 2;
  const int lseg = (tid & 3) * 8;

  const u16* Ag = A + (m0 + ldr) * K + lseg;
  const u16* Wg = W + (size_t)(n0 + ldr) * K + lseg;

  f32x4 acc[2][2] = {};

#pragma unroll 1
  for (int kc = 0; kc < K; kc += 32) {
    *(short8*)&As[ldr * 40 + lseg] = *(const short8*)(Ag + kc);
    *(short8*)&Wt[ldr * 40 + lseg] = *(const short8*)(Wg + kc);
    __syncthreads();
    short8 a0 = *(const short8*)&As[(wm * 32 + l15) * 40 + quad * 8];
    short8 a1 = *(const short8*)&As[(wm * 32 + 16 + l15) * 40 + quad * 8];
    short8 b0 = *(const short8*)&Wt[(wn * 32 + l15) * 40 + quad * 8];
    short8 b1 = *(const short8*)&Wt[(wn * 32 + 16 + l15) * 40 + quad * 8];
    acc[0][0] = __builtin_amdgcn_mfma_f32_16x16x32_bf16(a0, b0, acc[0][0], 0, 0, 0);
    acc[1][0] = __builtin_amdgcn_mfma_f32_16x16x32_bf16(a1, b0, acc[1][0], 0, 0, 0);
    acc[0][1] = __builtin_amdgcn_mfma_f32_16x16x32_bf16(a0, b1, acc[0][1], 0, 0, 0);
    acc[1][1] = __builtin_amdgcn_mfma_f32_16x16x32_bf16(a1, b1, acc[1][1], 0, 0, 0);
    __syncthreads();
  }

#pragma unroll
  for (int mi = 0; mi < 2; mi++)
#pragma unroll
    for (int ni = 0; ni < 2; ni++) {
      const int nl   = wn * 32 + ni * 16 + l15;   // 0..63 within tile
      const int ncol = n0 + nl;                   // global col
      const float bv = bias[ncol];
#pragma unroll
      for (int r = 0; r < 4; r++) {
        const size_t m = m0 + wm * 32 + mi * 16 + quad * 4 + r;
        float v = acc[mi][ni][r] + bv;
        if (EPI == 0) {
          v = v > 0.0f ? v : 0.01f * v;
          ((u16*)outp)[m * (size_t)N + ncol] = f2bf(v);
        } else if (EPI == 1) {
          const int tt = (int)(m >> 8), b = (int)(m & 255);
          const int q  = ncol >> 8, jc = ncol & 255;
          const int phh = jc >> 7, jl = jc & 127;
          ((u16*)outp)[(size_t)tt * 262144 + (size_t)(q >> 1) * 131072 +
                       (size_t)b * 512 + phh * 256 + (q & 1) * 128 + jl] =
              f2bf(v);
        } else {
          if (ncol < 32)
            ((float*)outp)[m * 32 + ncol] = tanhf(v);
          else
            ((float*)outp + 4194304)[m * 32 + ncol - 32] =
                log1pf(__expf(v)) + 1e-6f;
        }
      }
    }
}

// -------------------------------------------------------------- LSTM scan
// 32 blocks = 16 pairs x 2, pairs via runtime XCD discovery. Pair p owns
// batches [16p,16p+16); half ph owns h-dims [128ph,128ph+128) -> 512 W_hh
// rows register-resident as MFMA B-frags. Xbuf word = bf16(h2)|((t+1)<<16),
// layout [pair][parity][4 mg][jcol*4+mo]. Per step:
//   B1 -> acc=ig[t], own-half A-frags + 16 MFMAs -> wave0 polls partner 8KB
//   (others idle at B2, no vmcnt) -> B2 -> hid[t] stores, partner-half 16
//   MFMAs, ig[t+1] prefetch -> gate math -> publish (dual store) + own-half
//   LDS + pre stores. 2 lgkm-only barriers; parity dbuf prevents tag t+2
//   clobbering unconsumed tag t.
__global__ __launch_bounds__(512, 2) void lstm_scan(
    const u16* __restrict__ Whh,    // bf16 [1024][256]
    const int* __restrict__ dones,  // [512][256]
    const u16* ig,                  // bf16, ALIASES hid region (no restrict!)
    float* hid,                     // d_out + 8388608 floats (no restrict!)
    u16* __restrict__ pre_out,      // bf16 [131072][256] = leaky_relu(h2)
    u32* __restrict__ Xbuf,         // [16 pair][2 parity][4 mg][1024]
    u32* __restrict__ ctl) {        // [0..7]=cnt [8]=arrivals [16+x*32+r]=bid+1
  const int tid  = threadIdx.x;
  const int w    = tid >> 6;
  const int lane = tid & 63;
  const int quad = lane >> 4, l15 = lane & 15;

  __shared__ int s_pair[2];
  __shared__ __align__(16) u16 h_lds[2][16 * 264];  // parity dbuf
  __shared__ u32 dns_lds[512 * 4];  // [t][qw]: 4 batches/word, 1 byte each

  // ---- registration: discover XCC, build pairing (tid 0 only) ------------
  if (tid == 0) {
    u32 xcc;
    asm volatile("s_getreg_b32 %0, hwreg(HW_REG_XCC_ID)" : "=s"(xcc));
    xcc &= 7u;
    u32 rank = __hip_atomic_fetch_add(&ctl[xcc], 1u, __ATOMIC_RELAXED,
                                      __HIP_MEMORY_SCOPE_SYSTEM);
    if (rank < 32u)
      __hip_atomic_store(&ctl[16 + xcc * 32 + rank], blockIdx.x + 1u,
                         __ATOMIC_RELAXED, __HIP_MEMORY_SCOPE_SYSTEM);
    __hip_atomic_fetch_add(&ctl[8], 1u, __ATOMIC_RELEASE,
                           __HIP_MEMORY_SCOPE_SYSTEM);
    while (__hip_atomic_load(&ctl[8], __ATOMIC_ACQUIRE,
                             __HIP_MEMORY_SCOPE_SYSTEM) < 32u) {}
    // deterministic pairing: same-XCD pairs first, then pooled leftovers
    const u32 me = blockIdx.x + 1u;
    int pid = 0, half = 0, np = 0;
    u32 leftover[8]; int nl = 0;
    for (int xx = 0; xx < 8; xx++) {
      u32 c = __hip_atomic_load(&ctl[xx], __ATOMIC_RELAXED,
                                __HIP_MEMORY_SCOPE_SYSTEM);
      if (c > 32u) c = 32u;
      const u32 ce = c & ~1u;
      for (u32 r = 0; r < ce; r += 2) {
        u32 bA, bB;
        do { bA = __hip_atomic_load(&ctl[16 + xx * 32 + r], __ATOMIC_RELAXED,
                                    __HIP_MEMORY_SCOPE_SYSTEM); } while (!bA);
        do { bB = __hip_atomic_load(&ctl[16 + xx * 32 + r + 1], __ATOMIC_RELAXED,
                                    __HIP_MEMORY_SCOPE_SYSTEM); } while (!bB);
        if (bA == me) { pid = np; half = 0; }
        if (bB == me) { pid = np; half = 1; }
        np++;
      }
      if (c & 1u) {
        u32 bL;
        do { bL = __hip_atomic_load(&ctl[16 + xx * 32 + c - 1], __ATOMIC_RELAXED,
                                    __HIP_MEMORY_SCOPE_SYSTEM); } while (!bL);
        leftover[nl++] = bL;
      }
    }
    for (int k = 0; k + 1 < nl; k += 2) {
      if (leftover[k] == me)     { pid = np; half = 0; }
      if (leftover[k + 1] == me) { pid = np; half = 1; }
      np++;
    }
    s_pair[0] = pid;
    s_pair[1] = half;
  }
  __syncthreads();

  const int g  = s_pair[0];
  const int ph = s_pair[1];
  const int b0 = g * 16;
  const int jl   = w * 16 + l15;    // 0..127 local h-dim
  const int jcol = ph * 128 + jl;   // global h-dim
  const int jpart = (1 - ph) * 128; // partner half base (global j)

  // ---- persistent weight fragments: rows {q*256 + jcol}, q=i,f,g,o
  short8 wf[4][8];
#pragma unroll
  for (int q = 0; q < 4; q++) {
    const u16* wr = Whh + (size_t)(q * 256 + jcol) * 256;
#pragma unroll
    for (int kc = 0; kc < 8; kc++)
      wf[q][kc] = *(const short8*)(wr + kc * 32 + quad * 8);
  }

  // ---- dones -> LDS, packed 4 batches/word
  for (int i = tid; i < 2048; i += 512) {
    const int t = i >> 2, qw = i & 3;
    const int4 dv = *(const int4*)(dones + (size_t)t * 256 + b0 + qw * 4);
    dns_lds[i] = (u32)dv.x | ((u32)dv.y << 8) | ((u32)dv.z << 16) |
                 ((u32)dv.w << 24);
  }

  // ---- zero both h buffers (t=0 state is all-zero; t=0 reads buffer 0,
  //      partner half never polled at t=0 so must be zero there too)
  for (int i = tid; i < 2 * 16 * 264 / 2; i += 512) ((u32*)h_lds)[i] = 0;

  // ---- prefetch ig[0] (permuted layout)
  u16 igpf[16];
  {
    const u16* igr = ig + (size_t)b0 * 512 + ph * 256 + jl;
#pragma unroll
    for (int q = 0; q < 4; q++)
#pragma unroll
      for (int r = 0; r < 4; r++)
        igpf[q * 4 + r] = igr[(size_t)(q >> 1) * 131072 +
                              (size_t)(quad * 4 + r) * 512 + (q & 1) * 128];
  }
  __syncthreads();   // full barrier: drains LDS init + ig[0] loads

  const short8 z8 = {0, 0, 0, 0, 0, 0, 0, 0};
  float c4[4]   = {0.f, 0.f, 0.f, 0.f};
  float hown[4] = {0.f, 0.f, 0.f, 0.f};

#define CHK(v) (((v)[0] ^ want) | ((v)[1] ^ want) | ((v)[2] ^ want) | ((v)[3] ^ want))

  for (int t = 0; t < 512; t++) {
    // ---- B1: own-half LDS (written at end of t-1) ready ------------------
    asm volatile("s_waitcnt lgkmcnt(0)" ::: "memory");
    __builtin_amdgcn_s_barrier();
    __builtin_amdgcn_sched_barrier(0);

    // dones masks for this step
    const u32 dwk = dns_lds[t * 4 + quad];
    const u32 dwa = dns_lds[t * 4 + (l15 >> 2)];
    const bool ka = ((dwa >> ((l15 & 3) * 8)) & 0xffu) == 0u;

    // mask own state (pre-step h,c after masking == hid[t])
#pragma unroll
    for (int r = 0; r < 4; r++) {
      const float kv = ((dwk >> (8 * r)) & 0xffu) ? 0.f : 1.f;
      c4[r] *= kv; hown[r] *= kv;
    }

    // acc init from prefetched ig[t] — forces the ig[t] scoreboard wait
    // HERE (pre-B2) in every wave: alias proof for the post-B2 hid stores.
    f32x4 acc[4];
#pragma unroll
    for (int q = 0; q < 4; q++)
#pragma unroll
      for (int r = 0; r < 4; r++) acc[q][r] = bf2f(igpf[q * 4 + r]);

    // ---- own-half A-frags + 16 MFMAs (no partner dependence) -------------
    {
      short8 af;
#pragma unroll
      for (int kco = 0; kco < 4; kco++) {
        const int kc = ph * 4 + kco;
        af = *(const short8*)&h_lds[t & 1][l15 * 264 + kc * 32 + quad * 8];
        if (!ka) af = z8;
#pragma unroll
        for (int q = 0; q < 4; q++)
          acc[q] = __builtin_amdgcn_mfma_f32_16x16x32_bf16(af, wf[q][kc],
                                                           acc[q], 0, 0, 0);
      }
    }

    // ---- wave 0: poll partner half (8 dwordx4), scatter to LDS -----------
    if (w == 0 && t > 0) {
      const u32* pb = Xbuf + (size_t)(g * 2 + (t & 1)) * 4096 +
                      (size_t)(jpart + lane) * 4;
      const u32* p0 = pb;
      const u32* p1 = pb + 1024;
      const u32* p2 = pb + 2048;
      const u32* p3 = pb + 3072;
      const u32 want = (u32)t << 16;
      u32x4 a0, a1, b1, b2, c1, c2, d1, d2;
      for (;;) {
        asm volatile(
            "global_load_dwordx4 %0, %8, off sc0\n\t"
            "global_load_dwordx4 %1, %8, off offset:1024 sc0\n\t"
            "global_load_dwordx4 %2, %9, off sc0\n\t"
            "global_load_dwordx4 %3, %9, off offset:1024 sc0\n\t"
            "global_load_dwordx4 %4, %10, off sc0\n\t"
            "global_load_dwordx4 %5, %10, off offset:1024 sc0\n\t"
            "global_load_dwordx4 %6, %11, off sc0\n\t"
            "global_load_dwordx4 %7, %11, off offset:1024 sc0\n\t"
            "s_waitcnt vmcnt(0)"
            : "=&v"(a0), "=&v"(a1), "=&v"(b1), "=&v"(b2), "=&v"(c1),
              "=&v"(c2), "=&v"(d1), "=&v"(d2)
            : "v"(p0), "v"(p1), "v"(p2), "v"(p3)
            : "memory");
        if (((CHK(a0) | CHK(a1) | CHK(b1) | CHK(b2) | CHK(c1) | CHK(c2) |
              CHK(d1) | CHK(d2)) >> 16) == 0) break;
        asm volatile(
            "global_load_dwordx4 %0, %8, off sc0 sc1\n\t"
            "global_load_dwordx4 %1, %8, off offset:1024 sc0 sc1\n\t"
            "global_load_dwordx4 %2, %9, off sc0 sc1\n\t"
            "global_load_dwordx4 %3, %9, off offset:1024 sc0 sc1\n\t"
            "global_load_dwordx4 %4, %10, off sc0 sc1\n\t"
            "global_load_dwordx4 %5, %10, off offset:1024 sc0 sc1\n\t"
            "global_load_dwordx4 %6, %11, off sc0 sc1\n\t"
            "global_load_dwordx4 %7, %11, off offset:1024 sc0 sc1\n\t"
            "s_waitcnt vmcnt(0)"
            : "=&v"(a0), "=&v"(a1), "=&v"(b1), "=&v"(b2), "=&v"(c1),
              "=&v"(c2), "=&v"(d1), "=&v"(d2)
            : "v"(p0), "v"(p1), "v"(p2), "v"(p3)
            : "memory");
        if (((CHK(a0) | CHK(a1) | CHK(b1) | CHK(b2) | CHK(c1) | CHK(c2) |
              CHK(d1) | CHK(d2)) >> 16) == 0) break;
      }
      // scatter: load (mg,k) word i -> m = mg*4+i, jcol = jpart + k*64 + lane
      u16* hb = &h_lds[t & 1][0];
#pragma unroll
      for (int i = 0; i < 4; i++) {
        hb[(0 * 4 + i) * 264 + jpart + lane]      = (u16)a0[i];
        hb[(0 * 4 + i) * 264 + jpart + 64 + lane] = (u16)a1[i];
        hb[(1 * 4 + i) * 264 + jpart + lane]      = (u16)b1[i];
        hb[(1 * 4 + i) * 264 + jpart + 64 + lane] = (u16)b2[i];
        hb[(2 * 4 + i) * 264 + jpart + lane]      = (u16)c1[i];
        hb[(2 * 4 + i) * 264 + jpart + 64 + lane] = (u16)c2[i];
        hb[(3 * 4 + i) * 264 + jpart + lane]      = (u16)d1[i];
        hb[(3 * 4 + i) * 264 + jpart + 64 + lane] = (u16)d2[i];
      }
    }

    // ---- B2: partner half ready (lgkm-only; waves 1-7 did no vmcnt) ------
    asm volatile("s_waitcnt lgkmcnt(0)" ::: "memory");
    __builtin_amdgcn_s_barrier();
    __builtin_amdgcn_sched_barrier(0);

    // hid[t] stores: all waves passed their ig[t] register use before B2,
    // so the aliased bytes are dead. Same byte set per block (disjoint
    // across blocks).
    {
      float* h0 = hid + ((size_t)(t * 2) * 256 + b0) * 256 + jcol;
#pragma unroll
      for (int r = 0; r < 4; r++) {
        const int m = quad * 4 + r;
        h0[(size_t)m * 256] = hown[r];
        h0[(size_t)(256 + m) * 256] = c4[r];
      }
    }

    // prefetch ig[t+1] (post-B2: off the poller's critical segment; a full
    // step of latency cover; bytes overwritten only by hid[t+1] post-B2[t+1])
    if (t < 511) {
      const u16* igr = ig + (size_t)(t + 1) * 262144 + (size_t)b0 * 512 +
                       ph * 256 + jl;
#pragma unroll
      for (int q = 0; q < 4; q++)
#pragma unroll
        for (int r = 0; r < 4; r++)
          igpf[q * 4 + r] = igr[(size_t)(q >> 1) * 131072 +
                                (size_t)(quad * 4 + r) * 512 + (q & 1) * 128];
    }

    // ---- partner-half A-frags + 16 MFMAs ---------------------------------
    {
      short8 af;
#pragma unroll
      for (int kco = 0; kco < 4; kco++) {
        const int kc = (1 - ph) * 4 + kco;
        af = *(const short8*)&h_lds[t & 1][l15 * 264 + kc * 32 + quad * 8];
        if (!ka) af = z8;
#pragma unroll
        for (int q = 0; q < 4; q++)
          acc[q] = __builtin_amdgcn_mfma_f32_16x16x32_bf16(af, wf[q][kc],
                                                           acc[q], 0, 0, 0);
      }
    }

    // ---- gate math, then PUBLISH FIRST (exchange is the critical path) ---
    const u32 tagw = (u32)(t + 1) << 16;
    u32x4 xw;
#pragma unroll
    for (int r = 0; r < 4; r++) {
      const float iv = acc[0][r], fv = acc[1][r], gv = acc[2][r], ov = acc[3][r];
      const float c2 = fsigmoid(fv) * c4[r] + fsigmoid(iv) * ftanh(gv);
      const float h2 = fsigmoid(ov) * ftanh(c2);
      c4[r] = c2;
      hown[r] = h2;
      xw[r] = (u32)f2bf(h2) | tagw;
    }
    {
      u32* xo = Xbuf + (((size_t)(g * 2 + ((t + 1) & 1)) * 4 + quad) * 1024 +
                        jcol * 4);
      // plain -> local L2 (fast same-XCD rendezvous);
      // sc0 sc1 -> write-through LLC (liveness for any placement)
      asm volatile("global_store_dwordx4 %0, %1, off\n\t"
                   "global_store_dwordx4 %0, %1, off sc0 sc1"
                   :: "v"(xo), "v"(xw) : "memory");
    }
    u16* pr = pre_out + ((size_t)t * 256 + b0) * 256 + jcol;
#pragma unroll
    for (int r = 0; r < 4; r++) {
      const int m = quad * 4 + r;
      h_lds[(t + 1) & 1][m * 264 + jcol] = (u16)xw[r];  // own half for t+1
      const float pv = hown[r] > 0.0f ? hown[r] : 0.01f * hown[r];
      pr[(size_t)m * 256] = f2bf(pv);                   // pre = lrelu(h2)
    }
    // no trailing barrier: next step's B1 orders LDS; the tag protocol
    // needs no store drain before a flag (tag is in the data word).
  }
#undef CHK
}

// ---------------------------------------------------------------------------
extern "C" void kernel_launch(void* const* d_in, const int* in_sizes, int n_in,
                              void* d_out, int out_size, void* d_ws, size_t ws_size,
                              hipStream_t stream) {
  const float* x    = (const float*)d_in[0];
  const int*   dns  = (const int*)d_in[1];
  const float* W1   = (const float*)d_in[2];
  const float* b1   = (const float*)d_in[3];
  const float* Wih  = (const float*)d_in[4];
  const float* Whh  = (const float*)d_in[5];
  const float* bih  = (const float*)d_in[6];
  const float* bhh  = (const float*)d_in[7];
  const float* Wm   = (const float*)d_in[8];
  const float* bm   = (const float*)d_in[9];
  const float* Wsd  = (const float*)d_in[10];
  const float* bs   = (const float*)d_in[11];

  char* ws = (char*)d_ws;
  u16*   shb  = (u16*)(ws + OFF_SH);
  u16*   preb = (u16*)(ws + OFF_PRE);
  u16*   W1b  = (u16*)(ws + OFF_W1);
  u16*   Wihb = (u16*)(ws + OFF_WIH);
  u16*   Whhb = (u16*)(ws + OFF_WHH);
  u16*   Wcb  = (u16*)(ws + OFF_WCAT);
  float* bigv = (float*)(ws + OFF_BIG);
  float* bct  = (float*)(ws + OFF_BCAT);
  u32*   Xb   = (u32*)(ws + OFF_X);

  u16*   xb  = (u16*)d_out;                          // aliases means+stds
  u16*   igb = (u16*)((char*)d_out + 33554432);      // aliases hidden_outputs
  float* hid = (float*)d_out + 8388608;
  // ctl: last 2KB of the means+stds region — dead between A2 and the heads
  u32*   ctl = (u32*)((char*)d_out + 33554432 - 2048);

  k_conv_x<<<512, 256, 0, stream>>>(x, xb);
  k_small<<<64, 256, 0, stream>>>(W1, Wih, Whh, Wm, Wsd, bih, bhh, bm, bs,
                                  W1b, Wihb, Whhb, Wcb, bigv, bct);
  gemm_bt<128, 0><<<dim3(2048, 4), 256, 0, stream>>>(xb, W1b, b1, shb, 256);
  k_zero_ctl<<<1, 512, 0, stream>>>(ctl);
  gemm_bt<256, 1><<<dim3(2048, 16), 256, 0, stream>>>(shb, Wihb, bigv, igb, 1024);
  lstm_scan<<<32, 512, 0, stream>>>(Whhb, dns, igb, hid, preb, Xb, ctl);
  gemm_bt<256, 2><<<dim3(2048, 1), 256, 0, stream>>>(preb, Wcb, bct, d_out, 64);
}

// Round 6
// 2487.160 us; speedup vs baseline: 2.4135x; 2.4135x over previous
//
#include <hip/hip_runtime.h>

// ---------------------------------------------------------------------------
// GaussianGradientLSTMPolicy on MI355X
//   A0: fp32 -> bf16 converts (x, weights), bias fusions
//   A2: shared = leaky_relu(x @ W1^T + b1)                  [131072 x 256]
//   A3: ig     = shared @ W_ih^T + (b_ih + b_hh)  (permuted)[131072 x 1024]
//   B : persistent-register LSTM scan, block pairs exchange h halves
//       R9: = R8 (single-poller wave + K-split MFMA overlap) with the
//       register-allocation bug fixed:
//         R8 indexed wf[q][ph*4+kco] with RUNTIME ph -> compiler demoted the
//         128-VGPR weight array to scratch (VGPR_Count 128->76, 2.75x slow).
//         R9 reorders wf at LOAD time (slot j<4 = own-half k-slices ph*4+j,
//         slot 4+j = partner-half) so every MFMA uses a COMPILE-TIME index;
//         runtime ph appears only in load/LDS ADDRESSES (legal).
//       Structure (unchanged from R8):
//         - ONLY WAVE 0 polls the partner's 8KB half (8 dwordx4/lane,
//           alternating sc0 / sc0+sc1 legs -- always-live dual-path
//           protocol) and scatters it to LDS. Waves 1-7 execute NO vmcnt
//           in the loop; their stores drain in the background.
//         - K-split: 16 MFMAs over own h-half BEFORE the poll; partner-half
//           16 MFMAs after B2. Visibility latency overlaps own compute.
//         - acc-init (ig[t] use) before B2 in all waves => all ig[t] loads
//           complete before any post-B2 hid[t] store (alias safety).
//           ig[t+1] prefetch after B2.
//         - 2 lgkm-only barriers/step (B1 own-half LDS, B2 partner half).
//       XCD-discovery pairing kept (same-XCD pairs preferred).
//   C : means = tanh(pre@Wm^T+bm), stds = softplus(pre@Ws^T+bs)+eps
// Aliasing:
//   - x_bf16 lives in d_out[0 .. 32MiB) (means+stds region), consumed by A2
//   - ctl (pairing table) lives in the LAST 2KB of that region: dead after
//     A2 reads x_bf16, zeroed by k_zero_ctl (after A2), used by the scan,
//     overwritten by the heads GEMM (stds) afterwards.
//   - ig (bf16) lives in the d_out hidden_outputs region with a PERMUTED
//     layout such that the bytes block (g,ph) reads as ig[t] are exactly the
//     bytes it writes as hid[t]:
//       idx_u16(t,b,q,ph,jl) = t*262144 + (q>>1)*131072 + b*512
//                              + ph*256 + (q&1)*128 + jl
// ---------------------------------------------------------------------------

typedef __attribute__((ext_vector_type(8))) short short8;
typedef __attribute__((ext_vector_type(4))) float f32x4;
typedef __attribute__((ext_vector_type(4))) unsigned short u16x4;
typedef __attribute__((ext_vector_type(4))) unsigned int u32x4;
typedef unsigned short u16;
typedef unsigned int   u32;

// ws layout (bytes)
constexpr size_t OFF_SH   = 0;                      // shared bf16   67108864
constexpr size_t OFF_PRE  = 67108864;               // pre bf16      67108864
constexpr size_t OFF_W1   = 134217728;              // W1 bf16          65536
constexpr size_t OFF_WIH  = OFF_W1   + 65536;       // W_ih bf16       524288
constexpr size_t OFF_WHH  = OFF_WIH  + 524288;      // W_hh bf16       524288
constexpr size_t OFF_WCAT = OFF_WHH  + 524288;      // [Wm;Ws] bf16     32768
constexpr size_t OFF_BIG  = OFF_WCAT + 32768;       // b_ih+b_hh f32     4096
constexpr size_t OFF_BCAT = OFF_BIG  + 4096;        // [bm;bs] f32        256
constexpr size_t OFF_X    = OFF_BCAT + 256;         // h2 exchange     524288
// total ~136 MB

__device__ __forceinline__ u16 f2bf(float f) {
  union { float f; u32 u; } v; v.f = f;
  u32 u = v.u;
  return (u16)((u + 0x7fffu + ((u >> 16) & 1u)) >> 16);   // RNE
}
__device__ __forceinline__ float bf2f(u16 h) {
  union { u32 u; float f; } v; v.u = ((u32)h) << 16; return v.f;
}
__device__ __forceinline__ float fsigmoid(float x) {
  return 1.0f / (1.0f + __expf(-x));
}
__device__ __forceinline__ float ftanh(float x) {
  return 1.0f - 2.0f / (__expf(2.0f * x) + 1.0f);
}

// ---------------------------------------------------------------- converts
__global__ void k_conv_x(const float* __restrict__ x, u16* __restrict__ o) {
  const size_t stride = (size_t)gridDim.x * blockDim.x;
  for (size_t i = (size_t)blockIdx.x * blockDim.x + threadIdx.x;
       i < 16777216 / 4; i += stride) {
    f32x4 v = ((const f32x4*)x)[i];
    u16x4 r;
    r[0] = f2bf(v[0]); r[1] = f2bf(v[1]); r[2] = f2bf(v[2]); r[3] = f2bf(v[3]);
    ((u16x4*)o)[i] = r;
  }
}

__global__ void k_small(const float* __restrict__ W1, const float* __restrict__ Wih,
                        const float* __restrict__ Whh, const float* __restrict__ Wm,
                        const float* __restrict__ Ws,  const float* __restrict__ bih,
                        const float* __restrict__ bhh, const float* __restrict__ bm,
                        const float* __restrict__ bs,
                        u16* __restrict__ W1b, u16* __restrict__ Wihb,
                        u16* __restrict__ Whhb, u16* __restrict__ Wcatb,
                        float* __restrict__ bigv, float* __restrict__ bcatv) {
  const int stride = gridDim.x * blockDim.x;
  const int i0 = blockIdx.x * blockDim.x + threadIdx.x;
  for (int i = i0; i < 32768;  i += stride) W1b[i]  = f2bf(W1[i]);
  for (int i = i0; i < 262144; i += stride) Wihb[i] = f2bf(Wih[i]);
  for (int i = i0; i < 262144; i += stride) Whhb[i] = f2bf(Whh[i]);
  for (int i = i0; i < 8192;   i += stride) Wcatb[i]        = f2bf(Wm[i]);
  for (int i = i0; i < 8192;   i += stride) Wcatb[8192 + i] = f2bf(Ws[i]);
  for (int i = i0; i < 1024;   i += stride) bigv[i] = bih[i] + bhh[i];
  for (int i = i0; i < 32;     i += stride) bcatv[i]      = bm[i];
  for (int i = i0; i < 32;     i += stride) bcatv[32 + i] = bs[i];
}

// zero the pairing/control area (system scope -> LLC is the point of truth)
__global__ void k_zero_ctl(u32* __restrict__ ctl) {
  if (threadIdx.x < 512)
    __hip_atomic_store(&ctl[threadIdx.x], 0u, __ATOMIC_RELAXED,
                       __HIP_MEMORY_SCOPE_SYSTEM);
}

// ------------------------------------------------------------ generic GEMM
// C[M,N] = epi(A[M,K] @ W[N,K]^T + bias), bf16 in, fp32 acc.
// EPI 0: leaky_relu -> bf16 out (ld = N)
// EPI 1: bf16 out, permuted so scan-block (g,ph)'s ig[t] bytes == its hid[t]
// EPI 2: heads: n<32 -> tanh -> means(f32); n>=32 -> softplus+eps -> stds
template <int K, int EPI>
__global__ __launch_bounds__(256) void gemm_bt(const u16* __restrict__ A,
                                               const u16* __restrict__ W,
                                               const float* __restrict__ bias,
                                               void* __restrict__ outp, int N) {
  __shared__ __align__(16) u16 As[64 * 40];   // +8 pad: 2-way banks only
  __shared__ __align__(16) u16 Wt[64 * 40];
  const int tid  = threadIdx.x;
  const int lane = tid & 63;
  const int wv   = tid >> 6;
  const int quad = lane >> 4, l15 = lane & 15;
  const int wm = wv & 1, wn = wv >> 1;
  const size_t m0 = (size_t)blockIdx.x * 64;
  const int    n0 = blockIdx.y * 64;
  const int ldr  = tid >> 2;
  const int lseg = (tid & 3) * 8;

  const u16* Ag = A + (m0 + ldr) * K + lseg;
  const u16* Wg = W + (size_t)(n0 + ldr) * K + lseg;

  f32x4 acc[2][2] = {};

#pragma unroll 1
  for (int kc = 0; kc < K; kc += 32) {
    *(short8*)&As[ldr * 40 + lseg] = *(const short8*)(Ag + kc);
    *(short8*)&Wt[ldr * 40 + lseg] = *(const short8*)(Wg + kc);
    __syncthreads();
    short8 a0 = *(const short8*)&As[(wm * 32 + l15) * 40 + quad * 8];
    short8 a1 = *(const short8*)&As[(wm * 32 + 16 + l15) * 40 + quad * 8];
    short8 b0 = *(const short8*)&Wt[(wn * 32 + l15) * 40 + quad * 8];
    short8 b1 = *(const short8*)&Wt[(wn * 32 + 16 + l15) * 40 + quad * 8];
    acc[0][0] = __builtin_amdgcn_mfma_f32_16x16x32_bf16(a0, b0, acc[0][0], 0, 0, 0);
    acc[1][0] = __builtin_amdgcn_mfma_f32_16x16x32_bf16(a1, b0, acc[1][0], 0, 0, 0);
    acc[0][1] = __builtin_amdgcn_mfma_f32_16x16x32_bf16(a0, b1, acc[0][1], 0, 0, 0);
    acc[1][1] = __builtin_amdgcn_mfma_f32_16x16x32_bf16(a1, b1, acc[1][1], 0, 0, 0);
    __syncthreads();
  }

#pragma unroll
  for (int mi = 0; mi < 2; mi++)
#pragma unroll
    for (int ni = 0; ni < 2; ni++) {
      const int nl   = wn * 32 + ni * 16 + l15;   // 0..63 within tile
      const int ncol = n0 + nl;                   // global col
      const float bv = bias[ncol];
#pragma unroll
      for (int r = 0; r < 4; r++) {
        const size_t m = m0 + wm * 32 + mi * 16 + quad * 4 + r;
        float v = acc[mi][ni][r] + bv;
        if (EPI == 0) {
          v = v > 0.0f ? v : 0.01f * v;
          ((u16*)outp)[m * (size_t)N + ncol] = f2bf(v);
        } else if (EPI == 1) {
          const int tt = (int)(m >> 8), b = (int)(m & 255);
          const int q  = ncol >> 8, jc = ncol & 255;
          const int phh = jc >> 7, jl = jc & 127;
          ((u16*)outp)[(size_t)tt * 262144 + (size_t)(q >> 1) * 131072 +
                       (size_t)b * 512 + phh * 256 + (q & 1) * 128 + jl] =
              f2bf(v);
        } else {
          if (ncol < 32)
            ((float*)outp)[m * 32 + ncol] = tanhf(v);
          else
            ((float*)outp + 4194304)[m * 32 + ncol - 32] =
                log1pf(__expf(v)) + 1e-6f;
        }
      }
    }
}

// -------------------------------------------------------------- LSTM scan
// 32 blocks = 16 pairs x 2, pairs via runtime XCD discovery. Pair p owns
// batches [16p,16p+16); half ph owns h-dims [128ph,128ph+128) -> 512 W_hh
// rows register-resident as MFMA B-frags (wf slot j<4 = OWN-half k-slices,
// 4+j = partner-half; all MFMA indices compile-time). Xbuf word =
// bf16(h2)|((t+1)<<16), layout [pair][parity][4 mg][1024]. Per step:
//   B1 -> acc=ig[t], own-half 16 MFMAs -> wave0 polls partner 8KB (others
//   park at B2, no vmcnt) -> B2 -> hid[t] stores, ig[t+1] prefetch,
//   partner-half 16 MFMAs -> gate math -> publish (dual store) + own-half
//   LDS + pre stores. 2 lgkm-only barriers; parity dbuf prevents tag t+2
//   clobbering unconsumed tag t.
__global__ __launch_bounds__(512, 2) void lstm_scan(
    const u16* __restrict__ Whh,    // bf16 [1024][256]
    const int* __restrict__ dones,  // [512][256]
    const u16* ig,                  // bf16, ALIASES hid region (no restrict!)
    float* hid,                     // d_out + 8388608 floats (no restrict!)
    u16* __restrict__ pre_out,      // bf16 [131072][256] = leaky_relu(h2)
    u32* __restrict__ Xbuf,         // [16 pair][2 parity][4 mg][1024]
    u32* __restrict__ ctl) {        // [0..7]=cnt [8]=arrivals [16+x*32+r]=bid+1
  const int tid  = threadIdx.x;
  const int w    = tid >> 6;
  const int lane = tid & 63;
  const int quad = lane >> 4, l15 = lane & 15;

  __shared__ int s_pair[2];
  __shared__ __align__(16) u16 h_lds[2][16 * 264];  // parity dbuf
  __shared__ u32 dns_lds[512 * 4];  // [t][qw]: 4 batches/word, 1 byte each

  // ---- registration: discover XCC, build pairing (tid 0 only) ------------
  if (tid == 0) {
    u32 xcc;
    asm volatile("s_getreg_b32 %0, hwreg(HW_REG_XCC_ID)" : "=s"(xcc));
    xcc &= 7u;
    u32 rank = __hip_atomic_fetch_add(&ctl[xcc], 1u, __ATOMIC_RELAXED,
                                      __HIP_MEMORY_SCOPE_SYSTEM);
    if (rank < 32u)
      __hip_atomic_store(&ctl[16 + xcc * 32 + rank], blockIdx.x + 1u,
                         __ATOMIC_RELAXED, __HIP_MEMORY_SCOPE_SYSTEM);
    __hip_atomic_fetch_add(&ctl[8], 1u, __ATOMIC_RELEASE,
                           __HIP_MEMORY_SCOPE_SYSTEM);
    while (__hip_atomic_load(&ctl[8], __ATOMIC_ACQUIRE,
                             __HIP_MEMORY_SCOPE_SYSTEM) < 32u) {}
    // deterministic pairing: same-XCD pairs first, then pooled leftovers
    const u32 me = blockIdx.x + 1u;
    int pid = 0, half = 0, np = 0;
    u32 leftover[8]; int nl = 0;
    for (int xx = 0; xx < 8; xx++) {
      u32 c = __hip_atomic_load(&ctl[xx], __ATOMIC_RELAXED,
                                __HIP_MEMORY_SCOPE_SYSTEM);
      if (c > 32u) c = 32u;
      const u32 ce = c & ~1u;
      for (u32 r = 0; r < ce; r += 2) {
        u32 bA, bB;
        do { bA = __hip_atomic_load(&ctl[16 + xx * 32 + r], __ATOMIC_RELAXED,
                                    __HIP_MEMORY_SCOPE_SYSTEM); } while (!bA);
        do { bB = __hip_atomic_load(&ctl[16 + xx * 32 + r + 1], __ATOMIC_RELAXED,
                                    __HIP_MEMORY_SCOPE_SYSTEM); } while (!bB);
        if (bA == me) { pid = np; half = 0; }
        if (bB == me) { pid = np; half = 1; }
        np++;
      }
      if (c & 1u) {
        u32 bL;
        do { bL = __hip_atomic_load(&ctl[16 + xx * 32 + c - 1], __ATOMIC_RELAXED,
                                    __HIP_MEMORY_SCOPE_SYSTEM); } while (!bL);
        leftover[nl++] = bL;
      }
    }
    for (int k = 0; k + 1 < nl; k += 2) {
      if (leftover[k] == me)     { pid = np; half = 0; }
      if (leftover[k + 1] == me) { pid = np; half = 1; }
      np++;
    }
    s_pair[0] = pid;
    s_pair[1] = half;
  }
  __syncthreads();

  const int g  = __builtin_amdgcn_readfirstlane(s_pair[0]);
  const int ph = __builtin_amdgcn_readfirstlane(s_pair[1]);
  const int b0 = g * 16;
  const int jl   = w * 16 + l15;    // 0..127 local h-dim
  const int jcol = ph * 128 + jl;   // global h-dim
  const int jpart = (1 - ph) * 128; // partner half base (global j)
  const int kown  = ph * 4;         // own-half k-slice base (runtime, addr only)
  const int kpart = (1 - ph) * 4;   // partner-half k-slice base

  // ---- persistent weight fragments, REORDERED so MFMA indices are static:
  //      wf[q][j]   (j<4)  = k-slice (kown+j)   -- own half
  //      wf[q][4+j] (j<4)  = k-slice (kpart+j)  -- partner half
  short8 wf[4][8];
#pragma unroll
  for (int q = 0; q < 4; q++) {
    const u16* wr = Whh + (size_t)(q * 256 + jcol) * 256;
#pragma unroll
    for (int j = 0; j < 4; j++) {
      wf[q][j]     = *(const short8*)(wr + (kown + j) * 32 + quad * 8);
      wf[q][4 + j] = *(const short8*)(wr + (kpart + j) * 32 + quad * 8);
    }
  }

  // ---- dones -> LDS, packed 4 batches/word
  for (int i = tid; i < 2048; i += 512) {
    const int t = i >> 2, qw = i & 3;
    const int4 dv = *(const int4*)(dones + (size_t)t * 256 + b0 + qw * 4);
    dns_lds[i] = (u32)dv.x | ((u32)dv.y << 8) | ((u32)dv.z << 16) |
                 ((u32)dv.w << 24);
  }

  // ---- zero both h buffers (t=0 state is all-zero; t=0 reads buffer 0,
  //      partner half never polled at t=0 so must be zero there too)
  for (int i = tid; i < 2 * 16 * 264 / 2; i += 512) ((u32*)h_lds)[i] = 0;

  // ---- prefetch ig[0] (permuted layout)
  u16 igpf[16];
  {
    const u16* igr = ig + (size_t)b0 * 512 + ph * 256 + jl;
#pragma unroll
    for (int q = 0; q < 4; q++)
#pragma unroll
      for (int r = 0; r < 4; r++)
        igpf[q * 4 + r] = igr[(size_t)(q >> 1) * 131072 +
                              (size_t)(quad * 4 + r) * 512 + (q & 1) * 128];
  }
  __syncthreads();   // full barrier: drains LDS init + ig[0] loads

  const short8 z8 = {0, 0, 0, 0, 0, 0, 0, 0};
  float c4[4]   = {0.f, 0.f, 0.f, 0.f};
  float hown[4] = {0.f, 0.f, 0.f, 0.f};

#define CHK(v) (((v)[0] ^ want) | ((v)[1] ^ want) | ((v)[2] ^ want) | ((v)[3] ^ want))

  for (int t = 0; t < 512; t++) {
    // ---- B1: own-half LDS (written at end of t-1) ready ------------------
    asm volatile("s_waitcnt lgkmcnt(0)" ::: "memory");
    __builtin_amdgcn_s_barrier();
    __builtin_amdgcn_sched_barrier(0);

    // dones masks for this step
    const u32 dwk = dns_lds[t * 4 + quad];
    const u32 dwa = dns_lds[t * 4 + (l15 >> 2)];
    const bool ka = ((dwa >> ((l15 & 3) * 8)) & 0xffu) == 0u;

    // mask own state (pre-step h,c after masking == hid[t])
#pragma unroll
    for (int r = 0; r < 4; r++) {
      const float kv = ((dwk >> (8 * r)) & 0xffu) ? 0.f : 1.f;
      c4[r] *= kv; hown[r] *= kv;
    }

    // acc init from prefetched ig[t] — forces the ig[t] scoreboard wait
    // HERE (pre-B2) in every wave: alias proof for the post-B2 hid stores.
    f32x4 acc[4];
#pragma unroll
    for (int q = 0; q < 4; q++)
#pragma unroll
      for (int r = 0; r < 4; r++) acc[q][r] = bf2f(igpf[q * 4 + r]);

    // ---- own-half A-frags + 16 MFMAs (wf indices STATIC: j<4) ------------
#pragma unroll
    for (int kco = 0; kco < 4; kco++) {
      short8 af =
          *(const short8*)&h_lds[t & 1][l15 * 264 + (kown + kco) * 32 + quad * 8];
      if (!ka) af = z8;
#pragma unroll
      for (int q = 0; q < 4; q++)
        acc[q] = __builtin_amdgcn_mfma_f32_16x16x32_bf16(af, wf[q][kco],
                                                         acc[q], 0, 0, 0);
    }

    // ---- wave 0: poll partner half (8 dwordx4), scatter to LDS -----------
    if (w == 0 && t > 0) {
      const u32* pb = Xbuf + (size_t)(g * 2 + (t & 1)) * 4096 +
                      (size_t)(jpart + lane) * 4;
      const u32* p0 = pb;
      const u32* p1 = pb + 1024;
      const u32* p2 = pb + 2048;
      const u32* p3 = pb + 3072;
      const u32 want = (u32)t << 16;
      u32x4 a0, a1, b1, b2, c1, c2, d1, d2;
      for (;;) {
        asm volatile(
            "global_load_dwordx4 %0, %8, off sc0\n\t"
            "global_load_dwordx4 %1, %8, off offset:1024 sc0\n\t"
            "global_load_dwordx4 %2, %9, off sc0\n\t"
            "global_load_dwordx4 %3, %9, off offset:1024 sc0\n\t"
            "global_load_dwordx4 %4, %10, off sc0\n\t"
            "global_load_dwordx4 %5, %10, off offset:1024 sc0\n\t"
            "global_load_dwordx4 %6, %11, off sc0\n\t"
            "global_load_dwordx4 %7, %11, off offset:1024 sc0\n\t"
            "s_waitcnt vmcnt(0)"
            : "=&v"(a0), "=&v"(a1), "=&v"(b1), "=&v"(b2), "=&v"(c1),
              "=&v"(c2), "=&v"(d1), "=&v"(d2)
            : "v"(p0), "v"(p1), "v"(p2), "v"(p3)
            : "memory");
        if (((CHK(a0) | CHK(a1) | CHK(b1) | CHK(b2) | CHK(c1) | CHK(c2) |
              CHK(d1) | CHK(d2)) >> 16) == 0) break;
        asm volatile(
            "global_load_dwordx4 %0, %8, off sc0 sc1\n\t"
            "global_load_dwordx4 %1, %8, off offset:1024 sc0 sc1\n\t"
            "global_load_dwordx4 %2, %9, off sc0 sc1\n\t"
            "global_load_dwordx4 %3, %9, off offset:1024 sc0 sc1\n\t"
            "global_load_dwordx4 %4, %10, off sc0 sc1\n\t"
            "global_load_dwordx4 %5, %10, off offset:1024 sc0 sc1\n\t"
            "global_load_dwordx4 %6, %11, off sc0 sc1\n\t"
            "global_load_dwordx4 %7, %11, off offset:1024 sc0 sc1\n\t"
            "s_waitcnt vmcnt(0)"
            : "=&v"(a0), "=&v"(a1), "=&v"(b1), "=&v"(b2), "=&v"(c1),
              "=&v"(c2), "=&v"(d1), "=&v"(d2)
            : "v"(p0), "v"(p1), "v"(p2), "v"(p3)
            : "memory");
        if (((CHK(a0) | CHK(a1) | CHK(b1) | CHK(b2) | CHK(c1) | CHK(c2) |
              CHK(d1) | CHK(d2)) >> 16) == 0) break;
      }
      // scatter: load (mg,k) word i -> m = mg*4+i, jcol = jpart + k*64 + lane
      u16* hb = &h_lds[t & 1][0];
#pragma unroll
      for (int i = 0; i < 4; i++) {
        hb[(0 * 4 + i) * 264 + jpart + lane]      = (u16)a0[i];
        hb[(0 * 4 + i) * 264 + jpart + 64 + lane] = (u16)a1[i];
        hb[(1 * 4 + i) * 264 + jpart + lane]      = (u16)b1[i];
        hb[(1 * 4 + i) * 264 + jpart + 64 + lane] = (u16)b2[i];
        hb[(2 * 4 + i) * 264 + jpart + lane]      = (u16)c1[i];
        hb[(2 * 4 + i) * 264 + jpart + 64 + lane] = (u16)c2[i];
        hb[(3 * 4 + i) * 264 + jpart + lane]      = (u16)d1[i];
        hb[(3 * 4 + i) * 264 + jpart + 64 + lane] = (u16)d2[i];
      }
    }

    // ---- B2: partner half ready (lgkm-only; waves 1-7 did no vmcnt) ------
    asm volatile("s_waitcnt lgkmcnt(0)" ::: "memory");
    __builtin_amdgcn_s_barrier();
    __builtin_amdgcn_sched_barrier(0);

    // hid[t] stores: all waves passed their ig[t] register use before B2,
    // so the aliased bytes are dead. Same byte set per block (disjoint
    // across blocks).
    {
      float* h0 = hid + ((size_t)(t * 2) * 256 + b0) * 256 + jcol;
#pragma unroll
      for (int r = 0; r < 4; r++) {
        const int m = quad * 4 + r;
        h0[(size_t)m * 256] = hown[r];
        h0[(size_t)(256 + m) * 256] = c4[r];
      }
    }

    // prefetch ig[t+1] (post-B2: off the poller's critical segment; a full
    // step of latency cover; bytes overwritten only by hid[t+1] post-B2[t+1])
    if (t < 511) {
      const u16* igr = ig + (size_t)(t + 1) * 262144 + (size_t)b0 * 512 +
                       ph * 256 + jl;
#pragma unroll
      for (int q = 0; q < 4; q++)
#pragma unroll
        for (int r = 0; r < 4; r++)
          igpf[q * 4 + r] = igr[(size_t)(q >> 1) * 131072 +
                                (size_t)(quad * 4 + r) * 512 + (q & 1) * 128];
    }

    // ---- partner-half A-frags + 16 MFMAs (wf indices STATIC: 4+j) --------
#pragma unroll
    for (int kco = 0; kco < 4; kco++) {
      short8 af =
          *(const short8*)&h_lds[t & 1][l15 * 264 + (kpart + kco) * 32 + quad * 8];
      if (!ka) af = z8;
#pragma unroll
      for (int q = 0; q < 4; q++)
        acc[q] = __builtin_amdgcn_mfma_f32_16x16x32_bf16(af, wf[q][4 + kco],
                                                         acc[q], 0, 0, 0);
    }

    // ---- gate math, then PUBLISH FIRST (exchange is the critical path) ---
    const u32 tagw = (u32)(t + 1) << 16;
    u32x4 xw;
#pragma unroll
    for (int r = 0; r < 4; r++) {
      const float iv = acc[0][r], fv = acc[1][r], gv = acc[2][r], ov = acc[3][r];
      const float c2 = fsigmoid(fv) * c4[r] + fsigmoid(iv) * ftanh(gv);
      const float h2 = fsigmoid(ov) * ftanh(c2);
      c4[r] = c2;
      hown[r] = h2;
      xw[r] = (u32)f2bf(h2) | tagw;
    }
    {
      u32* xo = Xbuf + (((size_t)(g * 2 + ((t + 1) & 1)) * 4 + quad) * 1024 +
                        jcol * 4);
      // plain -> local L2 (fast same-XCD rendezvous);
      // sc0 sc1 -> write-through LLC (liveness for any placement)
      asm volatile("global_store_dwordx4 %0, %1, off\n\t"
                   "global_store_dwordx4 %0, %1, off sc0 sc1"
                   :: "v"(xo), "v"(xw) : "memory");
    }
    u16* pr = pre_out + ((size_t)t * 256 + b0) * 256 + jcol;
#pragma unroll
    for (int r = 0; r < 4; r++) {
      const int m = quad * 4 + r;
      h_lds[(t + 1) & 1][m * 264 + jcol] = (u16)xw[r];  // own half for t+1
      const float pv = hown[r] > 0.0f ? hown[r] : 0.01f * hown[r];
      pr[(size_t)m * 256] = f2bf(pv);                   // pre = lrelu(h2)
    }
    // no trailing barrier: next step's B1 orders LDS; the tag protocol
    // needs no store drain before a flag (tag is in the data word).
  }
#undef CHK
}

// ---------------------------------------------------------------------------
extern "C" void kernel_launch(void* const* d_in, const int* in_sizes, int n_in,
                              void* d_out, int out_size, void* d_ws, size_t ws_size,
                              hipStream_t stream) {
  const float* x    = (const float*)d_in[0];
  const int*   dns  = (const int*)d_in[1];
  const float* W1   = (const float*)d_in[2];
  const float* b1   = (const float*)d_in[3];
  const float* Wih  = (const float*)d_in[4];
  const float* Whh  = (const float*)d_in[5];
  const float* bih  = (const float*)d_in[6];
  const float* bhh  = (const float*)d_in[7];
  const float* Wm   = (const float*)d_in[8];
  const float* bm   = (const float*)d_in[9];
  const float* Wsd  = (const float*)d_in[10];
  const float* bs   = (const float*)d_in[11];

  char* ws = (char*)d_ws;
  u16*   shb  = (u16*)(ws + OFF_SH);
  u16*   preb = (u16*)(ws + OFF_PRE);
  u16*   W1b  = (u16*)(ws + OFF_W1);
  u16*   Wihb = (u16*)(ws + OFF_WIH);
  u16*   Whhb = (u16*)(ws + OFF_WHH);
  u16*   Wcb  = (u16*)(ws + OFF_WCAT);
  float* bigv = (float*)(ws + OFF_BIG);
  float* bct  = (float*)(ws + OFF_BCAT);
  u32*   Xb   = (u32*)(ws + OFF_X);

  u16*   xb  = (u16*)d_out;                          // aliases means+stds
  u16*   igb = (u16*)((char*)d_out + 33554432);      // aliases hidden_outputs
  float* hid = (float*)d_out + 8388608;
  // ctl: last 2KB of the means+stds region — dead between A2 and the heads
  u32*   ctl = (u32*)((char*)d_out + 33554432 - 2048);

  k_conv_x<<<512, 256, 0, stream>>>(x, xb);
  k_small<<<64, 256, 0, stream>>>(W1, Wih, Whh, Wm, Wsd, bih, bhh, bm, bs,
                                  W1b, Wihb, Whhb, Wcb, bigv, bct);
  gemm_bt<128, 0><<<dim3(2048, 4), 256, 0, stream>>>(xb, W1b, b1, shb, 256);
  k_zero_ctl<<<1, 512, 0, stream>>>(ctl);
  gemm_bt<256, 1><<<dim3(2048, 16), 256, 0, stream>>>(shb, Wihb, bigv, igb, 1024);
  lstm_scan<<<32, 512, 0, stream>>>(Whhb, dns, igb, hid, preb, Xb, ctl);
  gemm_bt<256, 2><<<dim3(2048, 1), 256, 0, stream>>>(preb, Wcb, bct, d_out, 64);
}

// Round 8
// 1940.806 us; speedup vs baseline: 3.0929x; 1.2815x over previous
//
#include <hip/hip_runtime.h>

// ---------------------------------------------------------------------------
// GaussianGradientLSTMPolicy on MI355X
//   A0: fp32 -> bf16 converts (x, weights), bias fusions
//   A2: shared = leaky_relu(x @ W1^T + b1)                  [131072 x 256]
//   A3: ig     = shared @ W_ih^T + (b_ih + b_hh)  (permuted)[131072 x 1024]
//   B : persistent-register LSTM scan, block pairs exchange h halves
//       R11: = R10 (4x batch-split: 128 blocks = 64 pairs x 4 batches,
//       publish ahead of bulk stores) with the R10 correctness bug fixed:
//         R10 stored hid[t] AFTER the gate math had overwritten hown/c4
//         with post-step values -> hidden_outputs held (h2,c2) instead of
//         the pre-step (h,c). R11 snapshots hpre/cpre before the gate math
//         and stores those.
//       Theory under test (from R10): the ~3.8us/step wall of R4-R9 is the
//       per-CU store backlog (~40KB/step) the tag store queues behind, not
//       rendezvous latency. R11 divides per-CU traffic by 4 and issues the
//       publish BEFORE the hid/pre burst.
//       Structure per step: B1 -> acc=ig[t] (alias-proof) -> own-half MFMAs
//       -> wave0 polls partner 2KB (single poller, dual-path sc0 / sc0+sc1,
//       live for any placement) -> B2 -> ig[t+1] prefetch -> partner-half
//       MFMAs -> gate math -> PUBLISH (dual store) -> hid/pre stores
//       (quad0 only; m-rows 4..15 are dead padding).
//       XCD-discovery pairing kept (same-XCD preferred); per-XCD table
//       capacity raised to 64 for the 128-block grid.
//   C : means = tanh(pre@Wm^T+bm), stds = softplus(pre@Ws^T+bs)+eps
// Aliasing:
//   - x_bf16 lives in d_out[0 .. 32MiB) (means+stds region), consumed by A2
//   - ctl (pairing table) lives in the LAST 4KB of that region: dead after
//     A2 reads x_bf16, zeroed by k_zero_ctl (after A2), used by the scan,
//     overwritten by the heads GEMM (stds) afterwards.
//   - ig (bf16) lives in the d_out hidden_outputs region with a PERMUTED
//     layout such that the bytes block (pair,ph) reads as ig[t] are exactly
//     the bytes it writes as hid[t] (per-(t,b) aliasing, batch-split safe):
//       idx_u16(t,b,q,ph,jl) = t*262144 + (q>>1)*131072 + b*512
//                              + ph*256 + (q&1)*128 + jl
// ---------------------------------------------------------------------------

typedef __attribute__((ext_vector_type(8))) short short8;
typedef __attribute__((ext_vector_type(4))) float f32x4;
typedef __attribute__((ext_vector_type(4))) unsigned short u16x4;
typedef __attribute__((ext_vector_type(4))) unsigned int u32x4;
typedef unsigned short u16;
typedef unsigned int   u32;

// ws layout (bytes)
constexpr size_t OFF_SH   = 0;                      // shared bf16   67108864
constexpr size_t OFF_PRE  = 67108864;               // pre bf16      67108864
constexpr size_t OFF_W1   = 134217728;              // W1 bf16          65536
constexpr size_t OFF_WIH  = OFF_W1   + 65536;       // W_ih bf16       524288
constexpr size_t OFF_WHH  = OFF_WIH  + 524288;      // W_hh bf16       524288
constexpr size_t OFF_WCAT = OFF_WHH  + 524288;      // [Wm;Ws] bf16     32768
constexpr size_t OFF_BIG  = OFF_WCAT + 32768;       // b_ih+b_hh f32     4096
constexpr size_t OFF_BCAT = OFF_BIG  + 4096;        // [bm;bs] f32        256
constexpr size_t OFF_X    = OFF_BCAT + 256;         // h2 exchange     524288
// total ~136 MB

__device__ __forceinline__ u16 f2bf(float f) {
  union { float f; u32 u; } v; v.f = f;
  u32 u = v.u;
  return (u16)((u + 0x7fffu + ((u >> 16) & 1u)) >> 16);   // RNE
}
__device__ __forceinline__ float bf2f(u16 h) {
  union { u32 u; float f; } v; v.u = ((u32)h) << 16; return v.f;
}
__device__ __forceinline__ float fsigmoid(float x) {
  return 1.0f / (1.0f + __expf(-x));
}
__device__ __forceinline__ float ftanh(float x) {
  return 1.0f - 2.0f / (__expf(2.0f * x) + 1.0f);
}

// ---------------------------------------------------------------- converts
__global__ void k_conv_x(const float* __restrict__ x, u16* __restrict__ o) {
  const size_t stride = (size_t)gridDim.x * blockDim.x;
  for (size_t i = (size_t)blockIdx.x * blockDim.x + threadIdx.x;
       i < 16777216 / 4; i += stride) {
    f32x4 v = ((const f32x4*)x)[i];
    u16x4 r;
    r[0] = f2bf(v[0]); r[1] = f2bf(v[1]); r[2] = f2bf(v[2]); r[3] = f2bf(v[3]);
    ((u16x4*)o)[i] = r;
  }
}

__global__ void k_small(const float* __restrict__ W1, const float* __restrict__ Wih,
                        const float* __restrict__ Whh, const float* __restrict__ Wm,
                        const float* __restrict__ Ws,  const float* __restrict__ bih,
                        const float* __restrict__ bhh, const float* __restrict__ bm,
                        const float* __restrict__ bs,
                        u16* __restrict__ W1b, u16* __restrict__ Wihb,
                        u16* __restrict__ Whhb, u16* __restrict__ Wcatb,
                        float* __restrict__ bigv, float* __restrict__ bcatv) {
  const int stride = gridDim.x * blockDim.x;
  const int i0 = blockIdx.x * blockDim.x + threadIdx.x;
  for (int i = i0; i < 32768;  i += stride) W1b[i]  = f2bf(W1[i]);
  for (int i = i0; i < 262144; i += stride) Wihb[i] = f2bf(Wih[i]);
  for (int i = i0; i < 262144; i += stride) Whhb[i] = f2bf(Whh[i]);
  for (int i = i0; i < 8192;   i += stride) Wcatb[i]        = f2bf(Wm[i]);
  for (int i = i0; i < 8192;   i += stride) Wcatb[8192 + i] = f2bf(Ws[i]);
  for (int i = i0; i < 1024;   i += stride) bigv[i] = bih[i] + bhh[i];
  for (int i = i0; i < 32;     i += stride) bcatv[i]      = bm[i];
  for (int i = i0; i < 32;     i += stride) bcatv[32 + i] = bs[i];
}

// zero the pairing/control area (system scope -> LLC is the point of truth)
__global__ void k_zero_ctl(u32* __restrict__ ctl) {
  for (int i = threadIdx.x; i < 1024; i += 512)
    __hip_atomic_store(&ctl[i], 0u, __ATOMIC_RELAXED,
                       __HIP_MEMORY_SCOPE_SYSTEM);
}

// ------------------------------------------------------------ generic GEMM
// C[M,N] = epi(A[M,K] @ W[N,K]^T + bias), bf16 in, fp32 acc.
// EPI 0: leaky_relu -> bf16 out (ld = N)
// EPI 1: bf16 out, permuted so scan-block's ig[t] bytes == its hid[t]
// EPI 2: heads: n<32 -> tanh -> means(f32); n>=32 -> softplus+eps -> stds
template <int K, int EPI>
__global__ __launch_bounds__(256) void gemm_bt(const u16* __restrict__ A,
                                               const u16* __restrict__ W,
                                               const float* __restrict__ bias,
                                               void* __restrict__ outp, int N) {
  __shared__ __align__(16) u16 As[64 * 40];   // +8 pad: 2-way banks only
  __shared__ __align__(16) u16 Wt[64 * 40];
  const int tid  = threadIdx.x;
  const int lane = tid & 63;
  const int wv   = tid >> 6;
  const int quad = lane >> 4, l15 = lane & 15;
  const int wm = wv & 1, wn = wv >> 1;
  const size_t m0 = (size_t)blockIdx.x * 64;
  const int    n0 = blockIdx.y * 64;
  const int ldr  = tid >> 2;
  const int lseg = (tid & 3) * 8;

  const u16* Ag = A + (m0 + ldr) * K + lseg;
  const u16* Wg = W + (size_t)(n0 + ldr) * K + lseg;

  f32x4 acc[2][2] = {};

#pragma unroll 1
  for (int kc = 0; kc < K; kc += 32) {
    *(short8*)&As[ldr * 40 + lseg] = *(const short8*)(Ag + kc);
    *(short8*)&Wt[ldr * 40 + lseg] = *(const short8*)(Wg + kc);
    __syncthreads();
    short8 a0 = *(const short8*)&As[(wm * 32 + l15) * 40 + quad * 8];
    short8 a1 = *(const short8*)&As[(wm * 32 + 16 + l15) * 40 + quad * 8];
    short8 b0 = *(const short8*)&Wt[(wn * 32 + l15) * 40 + quad * 8];
    short8 b1 = *(const short8*)&Wt[(wn * 32 + 16 + l15) * 40 + quad * 8];
    acc[0][0] = __builtin_amdgcn_mfma_f32_16x16x32_bf16(a0, b0, acc[0][0], 0, 0, 0);
    acc[1][0] = __builtin_amdgcn_mfma_f32_16x16x32_bf16(a1, b0, acc[1][0], 0, 0, 0);
    acc[0][1] = __builtin_amdgcn_mfma_f32_16x16x32_bf16(a0, b1, acc[0][1], 0, 0, 0);
    acc[1][1] = __builtin_amdgcn_mfma_f32_16x16x32_bf16(a1, b1, acc[1][1], 0, 0, 0);
    __syncthreads();
  }

#pragma unroll
  for (int mi = 0; mi < 2; mi++)
#pragma unroll
    for (int ni = 0; ni < 2; ni++) {
      const int nl   = wn * 32 + ni * 16 + l15;   // 0..63 within tile
      const int ncol = n0 + nl;                   // global col
      const float bv = bias[ncol];
#pragma unroll
      for (int r = 0; r < 4; r++) {
        const size_t m = m0 + wm * 32 + mi * 16 + quad * 4 + r;
        float v = acc[mi][ni][r] + bv;
        if (EPI == 0) {
          v = v > 0.0f ? v : 0.01f * v;
          ((u16*)outp)[m * (size_t)N + ncol] = f2bf(v);
        } else if (EPI == 1) {
          const int tt = (int)(m >> 8), b = (int)(m & 255);
          const int q  = ncol >> 8, jc = ncol & 255;
          const int phh = jc >> 7, jl = jc & 127;
          ((u16*)outp)[(size_t)tt * 262144 + (size_t)(q >> 1) * 131072 +
                       (size_t)b * 512 + phh * 256 + (q & 1) * 128 + jl] =
              f2bf(v);
        } else {
          if (ncol < 32)
            ((float*)outp)[m * 32 + ncol] = tanhf(v);
          else
            ((float*)outp + 4194304)[m * 32 + ncol - 32] =
                log1pf(__expf(v)) + 1e-6f;
        }
      }
    }
}

// -------------------------------------------------------------- LSTM scan
// 128 blocks = 64 pairs x 2 halves, pairs via runtime XCD discovery. Pair p
// owns batches [4p,4p+4); half ph owns h-dims [128ph,128ph+128) -> 512 W_hh
// rows register-resident (wf slot j<4 = own-half k-slices, 4+j = partner;
// all MFMA indices compile-time). Only m-rows 0..3 are real batches; rows
// 4..15 of the MFMA tile are zero padding (LDS rows never written). Xbuf
// word = bf16(h2)|((t+1)<<16), layout [pair][parity][j*4+m] (1024 words).
// Publish: quad0 threads, one dwordx4 each (j-dense). Poll: wave 0, two
// dwordx4 per lane. Parity dbuf prevents tag t+2 clobbering unconsumed t.
__global__ __launch_bounds__(512, 2) void lstm_scan(
    const u16* __restrict__ Whh,    // bf16 [1024][256]
    const int* __restrict__ dones,  // [512][256]
    const u16* ig,                  // bf16, ALIASES hid region (no restrict!)
    float* hid,                     // d_out + 8388608 floats (no restrict!)
    u16* __restrict__ pre_out,      // bf16 [131072][256] = leaky_relu(h2)
    u32* __restrict__ Xbuf,         // [64 pair][2 parity][1024 = j*4+m]
    u32* __restrict__ ctl) {        // [0..7]=cnt [8]=arrivals [16+x*64+r]=bid+1
  const int tid  = threadIdx.x;
  const int w    = tid >> 6;
  const int lane = tid & 63;
  const int quad = lane >> 4, l15 = lane & 15;

  __shared__ int s_pair[2];
  __shared__ __align__(16) u16 h_lds[2][16 * 264];  // parity dbuf; rows 4-15 stay 0
  __shared__ u32 dns_lds[512];      // [t]: 4 batches/word, 1 byte each

  // ---- registration: discover XCC, build pairing (tid 0 only) ------------
  if (tid == 0) {
    u32 xcc;
    asm volatile("s_getreg_b32 %0, hwreg(HW_REG_XCC_ID)" : "=s"(xcc));
    xcc &= 7u;
    u32 rank = __hip_atomic_fetch_add(&ctl[xcc], 1u, __ATOMIC_RELAXED,
                                      __HIP_MEMORY_SCOPE_SYSTEM);
    if (rank < 64u)
      __hip_atomic_store(&ctl[16 + xcc * 64 + rank], blockIdx.x + 1u,
                         __ATOMIC_RELAXED, __HIP_MEMORY_SCOPE_SYSTEM);
    __hip_atomic_fetch_add(&ctl[8], 1u, __ATOMIC_RELEASE,
                           __HIP_MEMORY_SCOPE_SYSTEM);
    while (__hip_atomic_load(&ctl[8], __ATOMIC_ACQUIRE,
                             __HIP_MEMORY_SCOPE_SYSTEM) < 128u) {}
    // deterministic pairing: same-XCD pairs first, then pooled leftovers
    const u32 me = blockIdx.x + 1u;
    int pid = 0, half = 0, np = 0;
    u32 leftover[8]; int nl = 0;
    for (int xx = 0; xx < 8; xx++) {
      u32 c = __hip_atomic_load(&ctl[xx], __ATOMIC_RELAXED,
                                __HIP_MEMORY_SCOPE_SYSTEM);
      if (c > 64u) c = 64u;
      const u32 ce = c & ~1u;
      for (u32 r = 0; r < ce; r += 2) {
        u32 bA, bB;
        do { bA = __hip_atomic_load(&ctl[16 + xx * 64 + r], __ATOMIC_RELAXED,
                                    __HIP_MEMORY_SCOPE_SYSTEM); } while (!bA);
        do { bB = __hip_atomic_load(&ctl[16 + xx * 64 + r + 1], __ATOMIC_RELAXED,
                                    __HIP_MEMORY_SCOPE_SYSTEM); } while (!bB);
        if (bA == me) { pid = np; half = 0; }
        if (bB == me) { pid = np; half = 1; }
        np++;
      }
      if (c & 1u) {
        u32 bL;
        do { bL = __hip_atomic_load(&ctl[16 + xx * 64 + c - 1], __ATOMIC_RELAXED,
                                    __HIP_MEMORY_SCOPE_SYSTEM); } while (!bL);
        leftover[nl++] = bL;
      }
    }
    for (int k = 0; k + 1 < nl; k += 2) {
      if (leftover[k] == me)     { pid = np; half = 0; }
      if (leftover[k + 1] == me) { pid = np; half = 1; }
      np++;
    }
    s_pair[0] = pid;
    s_pair[1] = half;
  }
  __syncthreads();

  const int g  = __builtin_amdgcn_readfirstlane(s_pair[0]);  // pair id, 0..63
  const int ph = __builtin_amdgcn_readfirstlane(s_pair[1]);
  const int b0 = g * 4;             // 4 batches per pair
  const int jl   = w * 16 + l15;    // 0..127 local h-dim
  const int jcol = ph * 128 + jl;   // global h-dim
  const int jpart = (1 - ph) * 128; // partner half base (global j)
  const int kown  = ph * 4;         // own-half k-slice base (addr only)
  const int kpart = (1 - ph) * 4;   // partner-half k-slice base

  // ---- persistent weight fragments, reordered so MFMA indices are static:
  //      wf[q][j] (j<4) = k-slice kown+j (own half); wf[q][4+j] = partner.
  short8 wf[4][8];
#pragma unroll
  for (int q = 0; q < 4; q++) {
    const u16* wr = Whh + (size_t)(q * 256 + jcol) * 256;
#pragma unroll
    for (int j = 0; j < 4; j++) {
      wf[q][j]     = *(const short8*)(wr + (kown + j) * 32 + quad * 8);
      wf[q][4 + j] = *(const short8*)(wr + (kpart + j) * 32 + quad * 8);
    }
  }

  // ---- dones -> LDS, 4 batches packed per word (one word per step)
  for (int i = tid; i < 512; i += 512) {
    const int4 dv = *(const int4*)(dones + (size_t)i * 256 + b0);
    dns_lds[i] = (u32)dv.x | ((u32)dv.y << 8) | ((u32)dv.z << 16) |
                 ((u32)dv.w << 24);
  }

  // ---- zero both h buffers (rows 4..15 stay zero forever -> dead MFMA rows)
  for (int i = tid; i < 2 * 16 * 264 / 2; i += 512) ((u32*)h_lds)[i] = 0;

  // ---- prefetch ig[0] (permuted layout; batch row r, same for all quads)
  u16 igpf[16];
  {
    const u16* igr = ig + (size_t)b0 * 512 + ph * 256 + jl;
#pragma unroll
    for (int q = 0; q < 4; q++)
#pragma unroll
      for (int r = 0; r < 4; r++)
        igpf[q * 4 + r] = igr[(size_t)(q >> 1) * 131072 +
                              (size_t)r * 512 + (q & 1) * 128];
  }
  __syncthreads();   // full barrier: drains LDS init + ig[0] loads

  const short8 z8 = {0, 0, 0, 0, 0, 0, 0, 0};
  float c4[4]   = {0.f, 0.f, 0.f, 0.f};
  float hown[4] = {0.f, 0.f, 0.f, 0.f};

#define CHK(v) (((v)[0] ^ want) | ((v)[1] ^ want) | ((v)[2] ^ want) | ((v)[3] ^ want))

  for (int t = 0; t < 512; t++) {
    // ---- B1: own-half LDS (written at end of t-1) ready ------------------
    asm volatile("s_waitcnt lgkmcnt(0)" ::: "memory");
    __builtin_amdgcn_s_barrier();
    __builtin_amdgcn_sched_barrier(0);

    // dones masks for this step (batch r = byte r; A-row mask via byte l15&3)
    const u32 dw = dns_lds[t];
    const bool ka = ((dw >> ((l15 & 3) * 8)) & 0xffu) == 0u;

    // mask own state; SNAPSHOT pre-step (h,c) == hid[t] for the stores
    float hpre[4], cpre[4];
#pragma unroll
    for (int r = 0; r < 4; r++) {
      const float kv = ((dw >> (8 * r)) & 0xffu) ? 0.f : 1.f;
      c4[r] *= kv; hown[r] *= kv;
      hpre[r] = hown[r]; cpre[r] = c4[r];
    }

    // acc init from prefetched ig[t] — forces the ig[t] scoreboard wait
    // HERE (pre-B2) in every wave: alias proof for the post-B2 hid stores.
    f32x4 acc[4];
#pragma unroll
    for (int q = 0; q < 4; q++)
#pragma unroll
      for (int r = 0; r < 4; r++) acc[q][r] = bf2f(igpf[q * 4 + r]);

    // ---- own-half A-frags + 16 MFMAs (rows 4..15 read zeros) -------------
#pragma unroll
    for (int kco = 0; kco < 4; kco++) {
      short8 af =
          *(const short8*)&h_lds[t & 1][l15 * 264 + (kown + kco) * 32 + quad * 8];
      if (!ka) af = z8;
#pragma unroll
      for (int q = 0; q < 4; q++)
        acc[q] = __builtin_amdgcn_mfma_f32_16x16x32_bf16(af, wf[q][kco],
                                                         acc[q], 0, 0, 0);
    }

    // ---- wave 0: poll partner half (2 dwordx4/lane), scatter to LDS ------
    if (w == 0 && t > 0) {
      const u32* pp = Xbuf + (size_t)(g * 2 + (t & 1)) * 1024 +
                      (size_t)(jpart + lane) * 4;
      const u32 want = (u32)t << 16;
      u32x4 v0, v1;
      for (;;) {
        asm volatile(
            "global_load_dwordx4 %0, %2, off sc0\n\t"
            "global_load_dwordx4 %1, %2, off offset:1024 sc0\n\t"
            "s_waitcnt vmcnt(0)"
            : "=&v"(v0), "=&v"(v1) : "v"(pp) : "memory");
        if (((CHK(v0) | CHK(v1)) >> 16) == 0) break;
        asm volatile(
            "global_load_dwordx4 %0, %2, off sc0 sc1\n\t"
            "global_load_dwordx4 %1, %2, off offset:1024 sc0 sc1\n\t"
            "s_waitcnt vmcnt(0)"
            : "=&v"(v0), "=&v"(v1) : "v"(pp) : "memory");
        if (((CHK(v0) | CHK(v1)) >> 16) == 0) break;
      }
      // scatter: word (j, m=i) -> h_lds row i, col j
      u16* hb = &h_lds[t & 1][0];
#pragma unroll
      for (int i = 0; i < 4; i++) {
        hb[i * 264 + jpart + lane]      = (u16)v0[i];
        hb[i * 264 + jpart + 64 + lane] = (u16)v1[i];
      }
    }

    // ---- B2: partner half ready (lgkm-only; waves 1-7 did no vmcnt) ------
    asm volatile("s_waitcnt lgkmcnt(0)" ::: "memory");
    __builtin_amdgcn_s_barrier();
    __builtin_amdgcn_sched_barrier(0);

    // prefetch ig[t+1] (bytes overwritten only by hid[t+1], post-B2 of t+1)
    if (t < 511) {
      const u16* igr = ig + (size_t)(t + 1) * 262144 + (size_t)b0 * 512 +
                       ph * 256 + jl;
#pragma unroll
      for (int q = 0; q < 4; q++)
#pragma unroll
        for (int r = 0; r < 4; r++)
          igpf[q * 4 + r] = igr[(size_t)(q >> 1) * 131072 +
                                (size_t)r * 512 + (q & 1) * 128];
    }

    // ---- partner-half A-frags + 16 MFMAs ---------------------------------
#pragma unroll
    for (int kco = 0; kco < 4; kco++) {
      short8 af =
          *(const short8*)&h_lds[t & 1][l15 * 264 + (kpart + kco) * 32 + quad * 8];
      if (!ka) af = z8;
#pragma unroll
      for (int q = 0; q < 4; q++)
        acc[q] = __builtin_amdgcn_mfma_f32_16x16x32_bf16(af, wf[q][4 + kco],
                                                         acc[q], 0, 0, 0);
    }

    // ---- gate math -> PUBLISH FIRST, bulk stores after -------------------
    const u32 tagw = (u32)(t + 1) << 16;
    u32x4 xw;
#pragma unroll
    for (int r = 0; r < 4; r++) {
      const float iv = acc[0][r], fv = acc[1][r], gv = acc[2][r], ov = acc[3][r];
      const float c2 = fsigmoid(fv) * c4[r] + fsigmoid(iv) * ftanh(gv);
      const float h2 = fsigmoid(ov) * ftanh(c2);
      c4[r] = c2;
      hown[r] = h2;
      xw[r] = (u32)f2bf(h2) | tagw;
    }
    if (quad == 0) {
      // publish: one dwordx4 (m=0..3 at this jcol); plain -> local L2,
      // sc0 sc1 -> LLC (liveness for any placement). Issued BEFORE the
      // hid/pre bulk so the tag never queues behind them.
      u32* xo = Xbuf + (size_t)(g * 2 + ((t + 1) & 1)) * 1024 + jcol * 4;
      asm volatile("global_store_dwordx4 %0, %1, off\n\t"
                   "global_store_dwordx4 %0, %1, off sc0 sc1"
                   :: "v"(xo), "v"(xw) : "memory");
      // hid[t] stores: PRE-step snapshot (hpre,cpre). Aliased ig[t] bytes
      // are dead (acc-init pre-B2 in all waves).
      float* h0 = hid + ((size_t)(t * 2) * 256 + b0) * 256 + jcol;
      u16* pr = pre_out + ((size_t)t * 256 + b0) * 256 + jcol;
#pragma unroll
      for (int r = 0; r < 4; r++) {
        h0[(size_t)r * 256] = hpre[r];
        h0[(size_t)(256 + r) * 256] = cpre[r];
        h_lds[(t + 1) & 1][r * 264 + jcol] = (u16)xw[r];  // own half for t+1
        const float pv = hown[r] > 0.0f ? hown[r] : 0.01f * hown[r];
        pr[(size_t)r * 256] = f2bf(pv);                   // pre = lrelu(h2)
      }
    }
    // no trailing barrier: next step's B1 orders LDS; the tag protocol
    // needs no store drain before a flag (tag is in the data word).
  }
#undef CHK
}

// ---------------------------------------------------------------------------
extern "C" void kernel_launch(void* const* d_in, const int* in_sizes, int n_in,
                              void* d_out, int out_size, void* d_ws, size_t ws_size,
                              hipStream_t stream) {
  const float* x    = (const float*)d_in[0];
  const int*   dns  = (const int*)d_in[1];
  const float* W1   = (const float*)d_in[2];
  const float* b1   = (const float*)d_in[3];
  const float* Wih  = (const float*)d_in[4];
  const float* Whh  = (const float*)d_in[5];
  const float* bih  = (const float*)d_in[6];
  const float* bhh  = (const float*)d_in[7];
  const float* Wm   = (const float*)d_in[8];
  const float* bm   = (const float*)d_in[9];
  const float* Wsd  = (const float*)d_in[10];
  const float* bs   = (const float*)d_in[11];

  char* ws = (char*)d_ws;
  u16*   shb  = (u16*)(ws + OFF_SH);
  u16*   preb = (u16*)(ws + OFF_PRE);
  u16*   W1b  = (u16*)(ws + OFF_W1);
  u16*   Wihb = (u16*)(ws + OFF_WIH);
  u16*   Whhb = (u16*)(ws + OFF_WHH);
  u16*   Wcb  = (u16*)(ws + OFF_WCAT);
  float* bigv = (float*)(ws + OFF_BIG);
  float* bct  = (float*)(ws + OFF_BCAT);
  u32*   Xb   = (u32*)(ws + OFF_X);

  u16*   xb  = (u16*)d_out;                          // aliases means+stds
  u16*   igb = (u16*)((char*)d_out + 33554432);      // aliases hidden_outputs
  float* hid = (float*)d_out + 8388608;
  // ctl: last 4KB of the means+stds region — dead between A2 and the heads
  u32*   ctl = (u32*)((char*)d_out + 33554432 - 4096);

  k_conv_x<<<512, 256, 0, stream>>>(x, xb);
  k_small<<<64, 256, 0, stream>>>(W1, Wih, Whh, Wm, Wsd, bih, bhh, bm, bs,
                                  W1b, Wihb, Whhb, Wcb, bigv, bct);
  gemm_bt<128, 0><<<dim3(2048, 4), 256, 0, stream>>>(xb, W1b, b1, shb, 256);
  k_zero_ctl<<<1, 512, 0, stream>>>(ctl);
  gemm_bt<256, 1><<<dim3(2048, 16), 256, 0, stream>>>(shb, Wihb, bigv, igb, 1024);
  lstm_scan<<<128, 512, 0, stream>>>(Whhb, dns, igb, hid, preb, Xb, ctl);
  gemm_bt<256, 2><<<dim3(2048, 1), 256, 0, stream>>>(preb, Wcb, bct, d_out, 64);
}